// Round 12
// baseline (231.449 us; speedup 1.0000x reference)
//
#include <hip/hip_runtime.h>

#define NBATCH 256
#define P 1024
#define Q 128
#define NS_LOOP 8

typedef _Float16 half8 __attribute__((ext_vector_type(8)));
typedef float f32x4 __attribute__((ext_vector_type(4)));
struct __attribute__((aligned(8))) Half4 { _Float16 x, y, z, w; };   // 8 bytes

// ---- swizzled fp16 machinery (counter-clean since r6) ----
__device__ __forceinline__ half8 frag_ld(const Half4* S, int rowbase, int slotbase, int lane) {
    const int r = rowbase + (lane & 15);
    const int g = (lane >> 4);
    const int rx = r & 15;
    const Half4 h1 = S[r * 32 + ((slotbase + g) ^ rx)];
    const Half4 h2 = S[r * 32 + ((slotbase + g + 4) ^ rx)];
    half8 v;
    v[0] = h1.x; v[1] = h1.y; v[2] = h1.z; v[3] = h1.w;
    v[4] = h2.x; v[5] = h2.y; v[6] = h2.z; v[7] = h2.w;
    return v;
}

__device__ __forceinline__ int cpos(int RB, int CB, int lane) {
    const int r = CB + (lane & 15);
    const int s = (RB >> 2) + (lane >> 4);
    return r * 32 + (s ^ (r & 15));
}

__device__ __forceinline__ f32x4 cread(const Half4* S, int p) {
    const Half4 h = S[p];
    f32x4 v;
    v[0] = (float)h.x; v[1] = (float)h.y; v[2] = (float)h.z; v[3] = (float)h.w;
    return v;
}

__device__ __forceinline__ void cwrite(Half4* S, int p, f32x4 v) {
    Half4 h;
    h.x = (_Float16)v[0]; h.y = (_Float16)v[1]; h.z = (_Float16)v[2]; h.w = (_Float16)v[3];
    S[p] = h;
}

__device__ __forceinline__ void cwrite_hl(Half4* Sh, Half4* Sl, int p, f32x4 v) {
    Half4 h, l;
    h.x = (_Float16)v[0]; h.y = (_Float16)v[1]; h.z = (_Float16)v[2]; h.w = (_Float16)v[3];
    l.x = (_Float16)(v[0] - (float)h.x);
    l.y = (_Float16)(v[1] - (float)h.y);
    l.z = (_Float16)(v[2] - (float)h.z);
    l.w = (_Float16)(v[3] - (float)h.w);
    Sh[p] = h; Sl[p] = l;
}

// ---- pitch-36 transposed-chunk fragment read for gram MFMA ----
__device__ __forceinline__ half8 frag_ld36(const _Float16* S, int rowbase, int lane) {
    const int r = rowbase + (lane & 15);
    const int g = lane >> 4;
    const Half4 h1 = *(const Half4*)(S + r * 36 + 4 * g);
    const Half4 h2 = *(const Half4*)(S + r * 36 + 16 + 4 * g);
    half8 v;
    v[0] = h1.x; v[1] = h1.y; v[2] = h1.z; v[3] = h1.w;
    v[4] = h2.x; v[5] = h2.y; v[6] = h2.z; v[7] = h2.w;
    return v;
}

// ---- gram helpers: load chunk -> regs; regs -> hi/lo LDS; MFMA a chunk ----
__device__ __forceinline__ void gram_load(const float* __restrict__ xb,
    const float* __restrict__ gb, float lr, int pbase, int ph, int q, float* tv)
{
#pragma unroll
    for (int t = 0; t < 2; ++t)
#pragma unroll
        for (int i = 0; i < 4; ++i) {
            const size_t off = (size_t)(pbase + ph * 4 + t * 16 + i) * Q + q;
            tv[t * 4 + i] = xb[off] - lr * gb[off];
        }
}

__device__ __forceinline__ void gram_store(_Float16* sHi, _Float16* sLo,
    int ph, int q, const float* tv)
{
#pragma unroll
    for (int t = 0; t < 2; ++t) {
        const int p0 = ph * 4 + t * 16;
        Half4 hq, lq;
        _Float16* hp = (_Float16*)&hq;
        _Float16* lp = (_Float16*)&lq;
#pragma unroll
        for (int i = 0; i < 4; ++i) {
            const float v = tv[t * 4 + i];
            const _Float16 hi = (_Float16)v;
            hp[i] = hi;
            lp[i] = (_Float16)(v - (float)hi);
        }
        *(Half4*)(sHi + q * 36 + p0) = hq;
        *(Half4*)(sLo + q * 36 + p0) = lq;
    }
}

__device__ __forceinline__ void gram_mfma(const _Float16* sHi, const _Float16* sLo,
    int RB, int lane, f32x4* acc)
{
    const half8 ahi = frag_ld36(sHi, RB, lane);
    const half8 alo = frag_ld36(sLo, RB, lane);
#pragma unroll
    for (int fj = 0; fj < 8; ++fj) {
        const half8 bhi = frag_ld36(sHi, fj * 16, lane);
        const half8 blo = frag_ld36(sLo, fj * 16, lane);
        acc[fj] = __builtin_amdgcn_mfma_f32_16x16x32_f16(ahi, bhi, acc[fj], 0, 0, 0);
        acc[fj] = __builtin_amdgcn_mfma_f32_16x16x32_f16(ahi, blo, acc[fj], 0, 0, 0);
        acc[fj] = __builtin_amdgcn_mfma_f32_16x16x32_f16(alo, bhi, acc[fj], 0, 0, 0);
    }
}

// ---------------------------------------------------------------------------
// Kernel 1: partial gram via fp16 MFMA hi/lo split + REGISTER PREFETCH.
// r11 counters: MfmaUtil 8.8%, VALUBusy 14%, HBM 22% -> pure latency bound
// (staging loads serialized against MFMA by the barrier). Prefetch next
// chunk into registers during the MFMA phase. Safe now: VGPR_Count=48,
// +16 prefetch regs ~= 75 peak << 128 cap (r4's spill had 64+ acc regs).
// ---------------------------------------------------------------------------
__global__ __launch_bounds__(512) void gram_kernel(
    const float* __restrict__ X, const float* __restrict__ G,
    const float* __restrict__ lrp, float* __restrict__ gpart, int npart)
{
    __shared__ _Float16 sHi[128 * 36];
    __shared__ _Float16 sLo[128 * 36];

    const int n = blockIdx.x / npart;
    const int part = blockIdx.x - n * npart;
    const int rows = P / npart;          // 256 at npart=4 -> 8 chunks
    const float lr = *lrp;
    const float* xb = X + (size_t)n * P * Q;
    const float* gb = G + (size_t)n * P * Q;

    const int tid = threadIdx.x;
    const int lane = tid & 63;
    const int wid = tid >> 6;
    const int RB = wid * 16;

    const int q = tid & 127;
    const int ph = tid >> 7;

    const f32x4 zero4 = {0.0f, 0.0f, 0.0f, 0.0f};
    f32x4 acc[8];
#pragma unroll
    for (int fj = 0; fj < 8; ++fj) acc[fj] = zero4;

    const int pstart = part * rows;
    const int nch = rows / 32;           // 8 (even; loop unrolled by 2)

    float tA[8], tB[8];
    gram_load(xb, gb, lr, pstart, ph, q, tA);

    for (int c = 0; c < nch; c += 2) {
        __syncthreads();                 // prev MFMA readers done
        gram_store(sHi, sLo, ph, q, tA);
        if (c + 1 < nch) gram_load(xb, gb, lr, pstart + (c + 1) * 32, ph, q, tB);
        __syncthreads();                 // chunk visible
        gram_mfma(sHi, sLo, RB, lane, acc);   // loads for c+1 in flight

        __syncthreads();
        gram_store(sHi, sLo, ph, q, tB);
        if (c + 2 < nch) gram_load(xb, gb, lr, pstart + (c + 2) * 32, ph, q, tA);
        __syncthreads();
        gram_mfma(sHi, sLo, RB, lane, acc);
    }

    float* gm = gpart + ((size_t)n * npart + part) * Q * Q;
    const int m0 = (lane >> 4) * 4;
    const int nn = lane & 15;
#pragma unroll
    for (int fj = 0; fj < 8; ++fj) {
#pragma unroll
        for (int j = 0; j < 4; ++j) {
            gm[(size_t)(RB + m0 + j) * Q + fj * 16 + nn] = acc[fj][j];
        }
    }
}

// ---------------------------------------------------------------------------
// Kernel 2: Newton-Schulz (fp16 MFMA) + fused fp32-grade refinement (r11).
// ---------------------------------------------------------------------------
__global__ __launch_bounds__(512) void ns_kernel(
    const float* __restrict__ gpart, int npart, float* __restrict__ Zg)
{
    __shared__ __align__(16) unsigned char pool[163840];
    Half4* bufA = (Half4*)pool;               // W ping / r-hi
    Half4* bufB = (Half4*)(pool + 32768);     // W pong / r-lo
    Half4* sZh  = (Half4*)(pool + 65536);     // Z iterate
    Half4* bufC = (Half4*)(pool + 98304);     // A-hi / u-hi
    Half4* bufD = (Half4*)(pool + 131072);    // A-lo / u-lo
    float* sRed = (float*)pool;               // aliases bufA head (guarded)

    const int n = blockIdx.x;
    const int tid = threadIdx.x;
    const float* gp = gpart + (size_t)n * npart * Q * Q;

    float4 gv[8];
    float ss = 0.0f;
#pragma unroll
    for (int t = 0; t < 8; ++t) {
        const int idx = tid + t * 512;
        float4 v = ((const float4*)gp)[idx];
        for (int pp = 1; pp < npart; ++pp) {
            const float4 w = ((const float4*)(gp + (size_t)pp * Q * Q))[idx];
            v.x += w.x; v.y += w.y; v.z += w.z; v.w += w.w;
        }
        gv[t] = v;
        ss += v.x * v.x + v.y * v.y + v.z * v.z + v.w * v.w;
    }
#pragma unroll
    for (int off = 32; off > 0; off >>= 1) ss += __shfl_down(ss, off, 64);
    if ((tid & 63) == 0) sRed[tid >> 6] = ss;
    __syncthreads();
    float csum = 0.0f;
#pragma unroll
    for (int w = 0; w < 8; ++w) csum += sRed[w];
    __syncthreads();   // sRed reads done before bufA init overwrites alias
    const float c = sqrtf(csum);
    const float rc = 1.0f / c;
    const float rs = 1.0f / sqrtf(c);

#pragma unroll
    for (int t = 0; t < 8; ++t) {
        const int idx = tid + t * 512;
        const int row = idx >> 5, c4 = idx & 31;
        const int slot = row * 32 + (c4 ^ (row & 15));
        float wv[4], zv[4];
        wv[0] = gv[t].x * rc; wv[1] = gv[t].y * rc;
        wv[2] = gv[t].z * rc; wv[3] = gv[t].w * rc;
        Half4 wh, wl, zh;
        _Float16* whp = (_Float16*)&wh;
        _Float16* wlp = (_Float16*)&wl;
        _Float16* zhp = (_Float16*)&zh;
#pragma unroll
        for (int j = 0; j < 4; ++j) {
            const _Float16 h = (_Float16)wv[j];
            whp[j] = h;
            wlp[j] = (_Float16)(wv[j] - (float)h);
            zv[j] = -0.5f * wv[j] + (((row >> 2) == c4 && (row & 3) == j) ? 1.5f : 0.0f);
            zhp[j] = (_Float16)zv[j];
        }
        bufA[slot] = wh;
        bufC[slot] = wh;
        bufD[slot] = wl;
        sZh[slot] = zh;
    }
    __syncthreads();

    const int lane = tid & 63;
    const int wid = tid >> 6;
    const int RB = wid * 16;
    const f32x4 zero4 = {0.0f, 0.0f, 0.0f, 0.0f};
    Half4* cur = bufA;
    Half4* scr = bufB;

    for (int it = 0; it < NS_LOOP; ++it) {
        f32x4 a1[8];
#pragma unroll
        for (int fj = 0; fj < 8; ++fj) a1[fj] = zero4;
#pragma unroll
        for (int kb = 0; kb < 4; ++kb) {
            const half8 af = frag_ld(cur, RB, kb * 8, lane);
#pragma unroll
            for (int fj = 0; fj < 8; ++fj) {
                const half8 bf = frag_ld(cur, fj * 16, kb * 8, lane);
                a1[fj] = __builtin_amdgcn_mfma_f32_16x16x32_f16(af, bf, a1[fj], 0, 0, 0);
            }
        }
#pragma unroll
        for (int fj = 0; fj < 8; ++fj) {
            const int p = cpos(RB, fj * 16, lane);
            cwrite(scr, p, 1.5f * cread(cur, p) - 0.5f * a1[fj]);
        }
        __syncthreads();

        f32x4 a2[8];
#pragma unroll
        for (int fj = 0; fj < 8; ++fj) a2[fj] = zero4;
#pragma unroll
        for (int kb = 0; kb < 4; ++kb) {
            const half8 af = frag_ld(scr, RB, kb * 8, lane);
#pragma unroll
            for (int fj = 0; fj < 8; ++fj) {
                const half8 bf = frag_ld(cur, fj * 16, kb * 8, lane);
                a2[fj] = __builtin_amdgcn_mfma_f32_16x16x32_f16(af, bf, a2[fj], 0, 0, 0);
            }
        }
        f32x4 wn[8];
#pragma unroll
        for (int fj = 0; fj < 8; ++fj) {
            const int p = cpos(RB, fj * 16, lane);
            wn[fj] = 1.5f * cread(scr, p) - 0.5f * a2[fj];
        }
        __syncthreads();
#pragma unroll
        for (int fj = 0; fj < 8; ++fj)
            cwrite(scr, cpos(RB, fj * 16, lane), wn[fj]);
        __syncthreads();

        f32x4 a3[8];
#pragma unroll
        for (int fj = 0; fj < 8; ++fj) a3[fj] = zero4;
#pragma unroll
        for (int kb = 0; kb < 4; ++kb) {
            const half8 af = frag_ld(scr, RB, kb * 8, lane);
#pragma unroll
            for (int fj = 0; fj < 8; ++fj) {
                const half8 bf = frag_ld(sZh, fj * 16, kb * 8, lane);
                a3[fj] = __builtin_amdgcn_mfma_f32_16x16x32_f16(af, bf, a3[fj], 0, 0, 0);
            }
        }
        f32x4 zn[8];
#pragma unroll
        for (int fj = 0; fj < 8; ++fj) {
            const int p = cpos(RB, fj * 16, lane);
            zn[fj] = 1.5f * cread(sZh, p) - 0.5f * a3[fj];
        }
        __syncthreads();
#pragma unroll
        for (int fj = 0; fj < 8; ++fj)
            cwrite(sZh, cpos(RB, fj * 16, lane), zn[fj]);
        __syncthreads();

        Half4* tmp = cur; cur = scr; scr = tmp;
    }

    // symmetrize z exactly
    {
        _Float16* zp = (_Float16*)sZh;
        for (int k = tid; k < Q * Q; k += 512) {
            const int r = k >> 7, cc = k & 127;
            if (r < cc) {
                const int i1 = (r * 32 + ((cc >> 2) ^ (r & 15))) * 4 + (cc & 3);
                const int i2 = (cc * 32 + ((r >> 2) ^ (cc & 15))) * 4 + (r & 3);
                const _Float16 av = (_Float16)(0.5f * ((float)zp[i1] + (float)zp[i2]));
                zp[i1] = av; zp[i2] = av;
            }
        }
    }
    __syncthreads();

    // racc = A*z -> cpos store = rows of (z*A)
    f32x4 racc[8];
#pragma unroll
    for (int fj = 0; fj < 8; ++fj) racc[fj] = zero4;
#pragma unroll
    for (int kb = 0; kb < 4; ++kb) {
        const half8 ah = frag_ld(bufC, RB, kb * 8, lane);
        const half8 al = frag_ld(bufD, RB, kb * 8, lane);
#pragma unroll
        for (int fj = 0; fj < 8; ++fj) {
            const half8 bz = frag_ld(sZh, fj * 16, kb * 8, lane);
            racc[fj] = __builtin_amdgcn_mfma_f32_16x16x32_f16(ah, bz, racc[fj], 0, 0, 0);
            racc[fj] = __builtin_amdgcn_mfma_f32_16x16x32_f16(al, bz, racc[fj], 0, 0, 0);
        }
    }
#pragma unroll
    for (int fj = 0; fj < 8; ++fj)
        cwrite_hl(bufA, bufB, cpos(RB, fj * 16, lane), racc[fj]);
    __syncthreads();

    // uacc = z*z -> bufC/bufD hi/lo
    f32x4 uacc[8];
#pragma unroll
    for (int fj = 0; fj < 8; ++fj) uacc[fj] = zero4;
#pragma unroll
    for (int kb = 0; kb < 4; ++kb) {
        const half8 az = frag_ld(sZh, RB, kb * 8, lane);
#pragma unroll
        for (int fj = 0; fj < 8; ++fj) {
            const half8 bz = frag_ld(sZh, fj * 16, kb * 8, lane);
            uacc[fj] = __builtin_amdgcn_mfma_f32_16x16x32_f16(az, bz, uacc[fj], 0, 0, 0);
        }
    }
#pragma unroll
    for (int fj = 0; fj < 8; ++fj)
        cwrite_hl(bufC, bufD, cpos(RB, fj * 16, lane), uacc[fj]);
    __syncthreads();

    // d = (z*A)*u ; Z_ref = rs*(1.5 z - 0.5 d)
    f32x4 dacc[8];
#pragma unroll
    for (int fj = 0; fj < 8; ++fj) dacc[fj] = zero4;
#pragma unroll
    for (int kb = 0; kb < 4; ++kb) {
        const half8 rh = frag_ld(bufA, RB, kb * 8, lane);
        const half8 rl = frag_ld(bufB, RB, kb * 8, lane);
#pragma unroll
        for (int fj = 0; fj < 8; ++fj) {
            const half8 uh = frag_ld(bufC, fj * 16, kb * 8, lane);
            const half8 ul = frag_ld(bufD, fj * 16, kb * 8, lane);
            dacc[fj] = __builtin_amdgcn_mfma_f32_16x16x32_f16(rh, uh, dacc[fj], 0, 0, 0);
            dacc[fj] = __builtin_amdgcn_mfma_f32_16x16x32_f16(rh, ul, dacc[fj], 0, 0, 0);
            dacc[fj] = __builtin_amdgcn_mfma_f32_16x16x32_f16(rl, uh, dacc[fj], 0, 0, 0);
        }
    }

    float* zo = Zg + (size_t)n * Q * Q;
    const int m0 = (lane >> 4) * 4;
    const int nn = lane & 15;
#pragma unroll
    for (int fj = 0; fj < 8; ++fj) {
        const f32x4 zq = cread(sZh, cpos(RB, fj * 16, lane));
#pragma unroll
        for (int j = 0; j < 4; ++j) {
            zo[(size_t)(RB + m0 + j) * Q + fj * 16 + nn] =
                rs * (1.5f * zq[j] - 0.5f * dacc[fj][j]);
        }
    }
}

// ---------------------------------------------------------------------------
// Kernel 3: out[n] = temp[n] @ Zg[n], fp16 MFMA (r8, counter-clean).
// ---------------------------------------------------------------------------
__global__ __launch_bounds__(512) void apply_kernel(
    const float* __restrict__ X, const float* __restrict__ G,
    const float* __restrict__ lrp, const float* __restrict__ Zg,
    float* __restrict__ out)
{
    __shared__ __align__(16) unsigned char pool[65536];
    Half4* sTh = (Half4*)pool;
    Half4* sZh = (Half4*)(pool + 32768);

    const int n = blockIdx.x >> 3;
    const int p0 = (blockIdx.x & 7) * 128;
    const int tid = threadIdx.x;
    const float lr = *lrp;
    const float* xb = X + (size_t)n * P * Q + (size_t)p0 * Q;
    const float* gb = G + (size_t)n * P * Q + (size_t)p0 * Q;
    const float* zb = Zg + (size_t)n * Q * Q;
    float* ob = out + (size_t)n * P * Q + (size_t)p0 * Q;

#pragma unroll
    for (int t = 0; t < 8; ++t) {
        const int idx = tid + t * 512;
        const int row = idx >> 5, c4 = idx & 31;
        const float4 v = ((const float4*)zb)[idx];
        Half4 h;
        h.x = (_Float16)v.x; h.y = (_Float16)v.y;
        h.z = (_Float16)v.z; h.w = (_Float16)v.w;
        sZh[row * 32 + (c4 ^ (row & 15))] = h;
    }
#pragma unroll
    for (int t = 0; t < 8; ++t) {
        const int idx = tid + t * 512;
        const int row = idx >> 5, c4 = idx & 31;
        const float4 xv = ((const float4*)xb)[idx];
        const float4 gv = ((const float4*)gb)[idx];
        Half4 h;
        h.x = (_Float16)(xv.x - lr * gv.x);
        h.y = (_Float16)(xv.y - lr * gv.y);
        h.z = (_Float16)(xv.z - lr * gv.z);
        h.w = (_Float16)(xv.w - lr * gv.w);
        sTh[row * 32 + (c4 ^ (row & 15))] = h;
    }
    __syncthreads();

    const int lane = tid & 63;
    const int wid = tid >> 6;
    const int RB = wid * 16;
    const f32x4 zero4 = {0.0f, 0.0f, 0.0f, 0.0f};

    f32x4 a[8];
#pragma unroll
    for (int fj = 0; fj < 8; ++fj) a[fj] = zero4;
#pragma unroll
    for (int kb = 0; kb < 4; ++kb) {
        const half8 af = frag_ld(sTh, RB, kb * 8, lane);
#pragma unroll
        for (int fj = 0; fj < 8; ++fj) {
            const half8 bf = frag_ld(sZh, fj * 16, kb * 8, lane);
            a[fj] = __builtin_amdgcn_mfma_f32_16x16x32_f16(af, bf, a[fj], 0, 0, 0);
        }
    }

    const int m0 = (lane >> 4) * 4;
    const int nn = lane & 15;
#pragma unroll
    for (int fj = 0; fj < 8; ++fj) {
#pragma unroll
        for (int j = 0; j < 4; ++j) {
            ob[(size_t)(RB + m0 + j) * Q + fj * 16 + nn] = a[fj][j];
        }
    }
}

extern "C" void kernel_launch(void* const* d_in, const int* in_sizes, int n_in,
                              void* d_out, int out_size, void* d_ws, size_t ws_size,
                              hipStream_t stream) {
    const float* X  = (const float*)d_in[0];
    const float* G  = (const float*)d_in[1];
    const float* lr = (const float*)d_in[2];
    float* outp = (float*)d_out;

    const size_t QQ = (size_t)Q * Q;
    const size_t mat = (size_t)NBATCH * QQ;

    const int npart_want = 4;
    const size_t need = (1 + npart_want) * mat * sizeof(float);
    const int npart = (ws_size >= need) ? npart_want : 1;

    float* Zg    = (float*)d_ws;
    float* gpart = Zg + mat;

    gram_kernel<<<NBATCH * npart, 512, 0, stream>>>(X, G, lr, gpart, npart);
    ns_kernel<<<NBATCH, 512, 0, stream>>>(gpart, npart, Zg);
    apply_kernel<<<NBATCH * 8, 512, 0, stream>>>(X, G, lr, Zg, outp);
}

// Round 13
// 224.648 us; speedup vs baseline: 1.0303x; 1.0303x over previous
//
#include <hip/hip_runtime.h>

#define NBATCH 256
#define P 1024
#define Q 128
#define NS_LOOP 8

typedef _Float16 half8 __attribute__((ext_vector_type(8)));
typedef float f32x4 __attribute__((ext_vector_type(4)));
struct __attribute__((aligned(8))) Half4 { _Float16 x, y, z, w; };   // 8 bytes

// raw workgroup barrier without HIP's implicit vmcnt(0) drain.
// lgkmcnt(0) guarantees ds_write visibility; memory clobbers pin LDS ops.
__device__ __forceinline__ void barrier_lds_only() {
    asm volatile("s_waitcnt lgkmcnt(0)" ::: "memory");
    __builtin_amdgcn_s_barrier();
    asm volatile("" ::: "memory");
}
__device__ __forceinline__ void barrier_plain() {
    asm volatile("" ::: "memory");
    __builtin_amdgcn_s_barrier();
    asm volatile("" ::: "memory");
}

// ---- swizzled fp16 machinery (counter-clean since r6) ----
__device__ __forceinline__ half8 frag_ld(const Half4* S, int rowbase, int slotbase, int lane) {
    const int r = rowbase + (lane & 15);
    const int g = (lane >> 4);
    const int rx = r & 15;
    const Half4 h1 = S[r * 32 + ((slotbase + g) ^ rx)];
    const Half4 h2 = S[r * 32 + ((slotbase + g + 4) ^ rx)];
    half8 v;
    v[0] = h1.x; v[1] = h1.y; v[2] = h1.z; v[3] = h1.w;
    v[4] = h2.x; v[5] = h2.y; v[6] = h2.z; v[7] = h2.w;
    return v;
}

__device__ __forceinline__ int cpos(int RB, int CB, int lane) {
    const int r = CB + (lane & 15);
    const int s = (RB >> 2) + (lane >> 4);
    return r * 32 + (s ^ (r & 15));
}

__device__ __forceinline__ f32x4 cread(const Half4* S, int p) {
    const Half4 h = S[p];
    f32x4 v;
    v[0] = (float)h.x; v[1] = (float)h.y; v[2] = (float)h.z; v[3] = (float)h.w;
    return v;
}

__device__ __forceinline__ void cwrite(Half4* S, int p, f32x4 v) {
    Half4 h;
    h.x = (_Float16)v[0]; h.y = (_Float16)v[1]; h.z = (_Float16)v[2]; h.w = (_Float16)v[3];
    S[p] = h;
}

__device__ __forceinline__ void cwrite_hl(Half4* Sh, Half4* Sl, int p, f32x4 v) {
    Half4 h, l;
    h.x = (_Float16)v[0]; h.y = (_Float16)v[1]; h.z = (_Float16)v[2]; h.w = (_Float16)v[3];
    l.x = (_Float16)(v[0] - (float)h.x);
    l.y = (_Float16)(v[1] - (float)h.y);
    l.z = (_Float16)(v[2] - (float)h.z);
    l.w = (_Float16)(v[3] - (float)h.w);
    Sh[p] = h; Sl[p] = l;
}

// ---- pitch-36 transposed-chunk fragment read for gram MFMA ----
__device__ __forceinline__ half8 frag_ld36(const _Float16* S, int rowbase, int lane) {
    const int r = rowbase + (lane & 15);
    const int g = lane >> 4;
    const Half4 h1 = *(const Half4*)(S + r * 36 + 4 * g);
    const Half4 h2 = *(const Half4*)(S + r * 36 + 16 + 4 * g);
    half8 v;
    v[0] = h1.x; v[1] = h1.y; v[2] = h1.z; v[3] = h1.w;
    v[4] = h2.x; v[5] = h2.y; v[6] = h2.z; v[7] = h2.w;
    return v;
}

// ---- gram helpers ----
__device__ __forceinline__ void gram_load(const float* __restrict__ xb,
    const float* __restrict__ gb, float lr, int pbase, int ph, int q, float* tv)
{
#pragma unroll
    for (int t = 0; t < 2; ++t)
#pragma unroll
        for (int i = 0; i < 4; ++i) {
            const size_t off = (size_t)(pbase + ph * 4 + t * 16 + i) * Q + q;
            tv[t * 4 + i] = xb[off] - lr * gb[off];
        }
}

// regs -> hi/lo LDS; also dump hi-cast temp to global (apply reads fp16).
__device__ __forceinline__ void gram_store(_Float16* sHi, _Float16* sLo,
    int ph, int q, const float* tv, _Float16* __restrict__ th, int pbase)
{
#pragma unroll
    for (int t = 0; t < 2; ++t) {
        const int p0 = ph * 4 + t * 16;
        Half4 hq, lq;
        _Float16* hp = (_Float16*)&hq;
        _Float16* lp = (_Float16*)&lq;
#pragma unroll
        for (int i = 0; i < 4; ++i) {
            const float v = tv[t * 4 + i];
            const _Float16 hi = (_Float16)v;
            hp[i] = hi;
            lp[i] = (_Float16)(v - (float)hi);
            if (th) th[(size_t)(pbase + p0 + i) * Q + q] = hi;  // 128B/instr coalesced
        }
        *(Half4*)(sHi + q * 36 + p0) = hq;
        *(Half4*)(sLo + q * 36 + p0) = lq;
    }
}

__device__ __forceinline__ void gram_mfma(const _Float16* sHi, const _Float16* sLo,
    int RB, int lane, f32x4* acc)
{
    const half8 ahi = frag_ld36(sHi, RB, lane);
    const half8 alo = frag_ld36(sLo, RB, lane);
#pragma unroll
    for (int fj = 0; fj < 8; ++fj) {
        const half8 bhi = frag_ld36(sHi, fj * 16, lane);
        const half8 blo = frag_ld36(sLo, fj * 16, lane);
        acc[fj] = __builtin_amdgcn_mfma_f32_16x16x32_f16(ahi, bhi, acc[fj], 0, 0, 0);
        acc[fj] = __builtin_amdgcn_mfma_f32_16x16x32_f16(ahi, blo, acc[fj], 0, 0, 0);
        acc[fj] = __builtin_amdgcn_mfma_f32_16x16x32_f16(alo, bhi, acc[fj], 0, 0, 0);
    }
}

// ---------------------------------------------------------------------------
// Kernel 1: partial gram, fp16 MFMA hi/lo + register prefetch + RAW BARRIERS.
// r12 lesson: __syncthreads drains vmcnt(0) -> prefetch was defeated. Raw
// s_barrier + lgkmcnt(0) (LDS visibility only) lets the prefetch loads float
// across the MFMA phase; compiler's vmcnt wait lands at next gram_store.
// ---------------------------------------------------------------------------
__global__ __launch_bounds__(512) void gram_kernel(
    const float* __restrict__ X, const float* __restrict__ G,
    const float* __restrict__ lrp, float* __restrict__ gpart, int npart,
    _Float16* __restrict__ tempH)
{
    __shared__ _Float16 sHi[128 * 36];
    __shared__ _Float16 sLo[128 * 36];

    const int n = blockIdx.x / npart;
    const int part = blockIdx.x - n * npart;
    const int rows = P / npart;
    const float lr = *lrp;
    const float* xb = X + (size_t)n * P * Q;
    const float* gb = G + (size_t)n * P * Q;
    _Float16* th = tempH ? tempH + (size_t)n * P * Q : (_Float16*)0;

    const int tid = threadIdx.x;
    const int lane = tid & 63;
    const int wid = tid >> 6;
    const int RB = wid * 16;
    const int q = tid & 127;
    const int ph = tid >> 7;

    const f32x4 zero4 = {0.0f, 0.0f, 0.0f, 0.0f};
    f32x4 acc[8];
#pragma unroll
    for (int fj = 0; fj < 8; ++fj) acc[fj] = zero4;

    const int pstart = part * rows;
    const int nch = rows / 32;           // even

    float tA[8], tB[8];
    gram_load(xb, gb, lr, pstart, ph, q, tA);

    for (int c = 0; c < nch; c += 2) {
        barrier_plain();                 // prev chunk's MFMA readers done
        gram_store(sHi, sLo, ph, q, tA, th, pstart + c * 32);
        if (c + 1 < nch) gram_load(xb, gb, lr, pstart + (c + 1) * 32, ph, q, tB);
        barrier_lds_only();              // ds_writes visible; vmcnt floats
        gram_mfma(sHi, sLo, RB, lane, acc);

        barrier_plain();
        gram_store(sHi, sLo, ph, q, tB, th, pstart + (c + 1) * 32);
        if (c + 2 < nch) gram_load(xb, gb, lr, pstart + (c + 2) * 32, ph, q, tA);
        barrier_lds_only();
        gram_mfma(sHi, sLo, RB, lane, acc);
    }

    float* gm = gpart + ((size_t)n * npart + part) * Q * Q;
    const int m0 = (lane >> 4) * 4;
    const int nn = lane & 15;
#pragma unroll
    for (int fj = 0; fj < 8; ++fj) {
#pragma unroll
        for (int j = 0; j < 4; ++j) {
            gm[(size_t)(RB + m0 + j) * Q + fj * 16 + nn] = acc[fj][j];
        }
    }
}

// ---------------------------------------------------------------------------
// Kernel 2: Newton-Schulz (fp16 MFMA) + fused fp32-grade refinement (r11/r12).
// ---------------------------------------------------------------------------
__global__ __launch_bounds__(512) void ns_kernel(
    const float* __restrict__ gpart, int npart, float* __restrict__ Zg)
{
    __shared__ __align__(16) unsigned char pool[163840];
    Half4* bufA = (Half4*)pool;
    Half4* bufB = (Half4*)(pool + 32768);
    Half4* sZh  = (Half4*)(pool + 65536);
    Half4* bufC = (Half4*)(pool + 98304);
    Half4* bufD = (Half4*)(pool + 131072);
    float* sRed = (float*)pool;

    const int n = blockIdx.x;
    const int tid = threadIdx.x;
    const float* gp = gpart + (size_t)n * npart * Q * Q;

    float4 gv[8];
    float ss = 0.0f;
#pragma unroll
    for (int t = 0; t < 8; ++t) {
        const int idx = tid + t * 512;
        float4 v = ((const float4*)gp)[idx];
        for (int pp = 1; pp < npart; ++pp) {
            const float4 w = ((const float4*)(gp + (size_t)pp * Q * Q))[idx];
            v.x += w.x; v.y += w.y; v.z += w.z; v.w += w.w;
        }
        gv[t] = v;
        ss += v.x * v.x + v.y * v.y + v.z * v.z + v.w * v.w;
    }
#pragma unroll
    for (int off = 32; off > 0; off >>= 1) ss += __shfl_down(ss, off, 64);
    if ((tid & 63) == 0) sRed[tid >> 6] = ss;
    __syncthreads();
    float csum = 0.0f;
#pragma unroll
    for (int w = 0; w < 8; ++w) csum += sRed[w];
    __syncthreads();
    const float c = sqrtf(csum);
    const float rc = 1.0f / c;
    const float rs = 1.0f / sqrtf(c);

#pragma unroll
    for (int t = 0; t < 8; ++t) {
        const int idx = tid + t * 512;
        const int row = idx >> 5, c4 = idx & 31;
        const int slot = row * 32 + (c4 ^ (row & 15));
        float wv[4], zv[4];
        wv[0] = gv[t].x * rc; wv[1] = gv[t].y * rc;
        wv[2] = gv[t].z * rc; wv[3] = gv[t].w * rc;
        Half4 wh, wl, zh;
        _Float16* whp = (_Float16*)&wh;
        _Float16* wlp = (_Float16*)&wl;
        _Float16* zhp = (_Float16*)&zh;
#pragma unroll
        for (int j = 0; j < 4; ++j) {
            const _Float16 h = (_Float16)wv[j];
            whp[j] = h;
            wlp[j] = (_Float16)(wv[j] - (float)h);
            zv[j] = -0.5f * wv[j] + (((row >> 2) == c4 && (row & 3) == j) ? 1.5f : 0.0f);
            zhp[j] = (_Float16)zv[j];
        }
        bufA[slot] = wh;
        bufC[slot] = wh;
        bufD[slot] = wl;
        sZh[slot] = zh;
    }
    __syncthreads();

    const int lane = tid & 63;
    const int wid = tid >> 6;
    const int RB = wid * 16;
    const f32x4 zero4 = {0.0f, 0.0f, 0.0f, 0.0f};
    Half4* cur = bufA;
    Half4* scr = bufB;

    for (int it = 0; it < NS_LOOP; ++it) {
        f32x4 a1[8];
#pragma unroll
        for (int fj = 0; fj < 8; ++fj) a1[fj] = zero4;
#pragma unroll
        for (int kb = 0; kb < 4; ++kb) {
            const half8 af = frag_ld(cur, RB, kb * 8, lane);
#pragma unroll
            for (int fj = 0; fj < 8; ++fj) {
                const half8 bf = frag_ld(cur, fj * 16, kb * 8, lane);
                a1[fj] = __builtin_amdgcn_mfma_f32_16x16x32_f16(af, bf, a1[fj], 0, 0, 0);
            }
        }
#pragma unroll
        for (int fj = 0; fj < 8; ++fj) {
            const int p = cpos(RB, fj * 16, lane);
            cwrite(scr, p, 1.5f * cread(cur, p) - 0.5f * a1[fj]);
        }
        __syncthreads();

        f32x4 a2[8];
#pragma unroll
        for (int fj = 0; fj < 8; ++fj) a2[fj] = zero4;
#pragma unroll
        for (int kb = 0; kb < 4; ++kb) {
            const half8 af = frag_ld(scr, RB, kb * 8, lane);
#pragma unroll
            for (int fj = 0; fj < 8; ++fj) {
                const half8 bf = frag_ld(cur, fj * 16, kb * 8, lane);
                a2[fj] = __builtin_amdgcn_mfma_f32_16x16x32_f16(af, bf, a2[fj], 0, 0, 0);
            }
        }
        f32x4 wn[8];
#pragma unroll
        for (int fj = 0; fj < 8; ++fj) {
            const int p = cpos(RB, fj * 16, lane);
            wn[fj] = 1.5f * cread(scr, p) - 0.5f * a2[fj];
        }
        __syncthreads();
#pragma unroll
        for (int fj = 0; fj < 8; ++fj)
            cwrite(scr, cpos(RB, fj * 16, lane), wn[fj]);
        __syncthreads();

        f32x4 a3[8];
#pragma unroll
        for (int fj = 0; fj < 8; ++fj) a3[fj] = zero4;
#pragma unroll
        for (int kb = 0; kb < 4; ++kb) {
            const half8 af = frag_ld(scr, RB, kb * 8, lane);
#pragma unroll
            for (int fj = 0; fj < 8; ++fj) {
                const half8 bf = frag_ld(sZh, fj * 16, kb * 8, lane);
                a3[fj] = __builtin_amdgcn_mfma_f32_16x16x32_f16(af, bf, a3[fj], 0, 0, 0);
            }
        }
        f32x4 zn[8];
#pragma unroll
        for (int fj = 0; fj < 8; ++fj) {
            const int p = cpos(RB, fj * 16, lane);
            zn[fj] = 1.5f * cread(sZh, p) - 0.5f * a3[fj];
        }
        __syncthreads();
#pragma unroll
        for (int fj = 0; fj < 8; ++fj)
            cwrite(sZh, cpos(RB, fj * 16, lane), zn[fj]);
        __syncthreads();

        Half4* tmp = cur; cur = scr; scr = tmp;
    }

    // symmetrize z exactly
    {
        _Float16* zp = (_Float16*)sZh;
        for (int k = tid; k < Q * Q; k += 512) {
            const int r = k >> 7, cc = k & 127;
            if (r < cc) {
                const int i1 = (r * 32 + ((cc >> 2) ^ (r & 15))) * 4 + (cc & 3);
                const int i2 = (cc * 32 + ((r >> 2) ^ (cc & 15))) * 4 + (r & 3);
                const _Float16 av = (_Float16)(0.5f * ((float)zp[i1] + (float)zp[i2]));
                zp[i1] = av; zp[i2] = av;
            }
        }
    }
    __syncthreads();

    // racc = A*z -> cpos store = rows of (z*A)
    f32x4 racc[8];
#pragma unroll
    for (int fj = 0; fj < 8; ++fj) racc[fj] = zero4;
#pragma unroll
    for (int kb = 0; kb < 4; ++kb) {
        const half8 ah = frag_ld(bufC, RB, kb * 8, lane);
        const half8 al = frag_ld(bufD, RB, kb * 8, lane);
#pragma unroll
        for (int fj = 0; fj < 8; ++fj) {
            const half8 bz = frag_ld(sZh, fj * 16, kb * 8, lane);
            racc[fj] = __builtin_amdgcn_mfma_f32_16x16x32_f16(ah, bz, racc[fj], 0, 0, 0);
            racc[fj] = __builtin_amdgcn_mfma_f32_16x16x32_f16(al, bz, racc[fj], 0, 0, 0);
        }
    }
#pragma unroll
    for (int fj = 0; fj < 8; ++fj)
        cwrite_hl(bufA, bufB, cpos(RB, fj * 16, lane), racc[fj]);
    __syncthreads();

    // uacc = z*z -> bufC/bufD hi/lo
    f32x4 uacc[8];
#pragma unroll
    for (int fj = 0; fj < 8; ++fj) uacc[fj] = zero4;
#pragma unroll
    for (int kb = 0; kb < 4; ++kb) {
        const half8 az = frag_ld(sZh, RB, kb * 8, lane);
#pragma unroll
        for (int fj = 0; fj < 8; ++fj) {
            const half8 bz = frag_ld(sZh, fj * 16, kb * 8, lane);
            uacc[fj] = __builtin_amdgcn_mfma_f32_16x16x32_f16(az, bz, uacc[fj], 0, 0, 0);
        }
    }
#pragma unroll
    for (int fj = 0; fj < 8; ++fj)
        cwrite_hl(bufC, bufD, cpos(RB, fj * 16, lane), uacc[fj]);
    __syncthreads();

    // d = (z*A)*u ; Z_ref = rs*(1.5 z - 0.5 d)
    f32x4 dacc[8];
#pragma unroll
    for (int fj = 0; fj < 8; ++fj) dacc[fj] = zero4;
#pragma unroll
    for (int kb = 0; kb < 4; ++kb) {
        const half8 rh = frag_ld(bufA, RB, kb * 8, lane);
        const half8 rl = frag_ld(bufB, RB, kb * 8, lane);
#pragma unroll
        for (int fj = 0; fj < 8; ++fj) {
            const half8 uh = frag_ld(bufC, fj * 16, kb * 8, lane);
            const half8 ul = frag_ld(bufD, fj * 16, kb * 8, lane);
            dacc[fj] = __builtin_amdgcn_mfma_f32_16x16x32_f16(rh, uh, dacc[fj], 0, 0, 0);
            dacc[fj] = __builtin_amdgcn_mfma_f32_16x16x32_f16(rh, ul, dacc[fj], 0, 0, 0);
            dacc[fj] = __builtin_amdgcn_mfma_f32_16x16x32_f16(rl, uh, dacc[fj], 0, 0, 0);
        }
    }

    float* zo = Zg + (size_t)n * Q * Q;
    const int m0 = (lane >> 4) * 4;
    const int nn = lane & 15;
#pragma unroll
    for (int fj = 0; fj < 8; ++fj) {
        const f32x4 zq = cread(sZh, cpos(RB, fj * 16, lane));
#pragma unroll
        for (int j = 0; j < 4; ++j) {
            zo[(size_t)(RB + m0 + j) * Q + fj * 16 + nn] =
                rs * (1.5f * zq[j] - 0.5f * dacc[fj][j]);
        }
    }
}

// ---------------------------------------------------------------------------
// Kernel 3: out[n] = temp[n] @ Zg[n], fp16 MFMA. Dual staging path:
// use_th=1 -> read fp16 temp (tempH from gram; identical values to the
// fp32->fp16 cast this kernel did before -> bit-identical output, half the
// stage bytes). use_th=0 -> legacy X,G path.
// ---------------------------------------------------------------------------
__global__ __launch_bounds__(512) void apply_kernel(
    const float* __restrict__ X, const float* __restrict__ G,
    const float* __restrict__ lrp, const float* __restrict__ Zg,
    const _Float16* __restrict__ tempH, int use_th,
    float* __restrict__ out)
{
    __shared__ __align__(16) unsigned char pool[65536];
    Half4* sTh = (Half4*)pool;
    Half4* sZh = (Half4*)(pool + 32768);

    const int n = blockIdx.x >> 3;
    const int p0 = (blockIdx.x & 7) * 128;
    const int tid = threadIdx.x;
    const float* zb = Zg + (size_t)n * Q * Q;
    float* ob = out + (size_t)n * P * Q + (size_t)p0 * Q;

#pragma unroll
    for (int t = 0; t < 8; ++t) {
        const int idx = tid + t * 512;
        const int row = idx >> 5, c4 = idx & 31;
        const float4 v = ((const float4*)zb)[idx];
        Half4 h;
        h.x = (_Float16)v.x; h.y = (_Float16)v.y;
        h.z = (_Float16)v.z; h.w = (_Float16)v.w;
        sZh[row * 32 + (c4 ^ (row & 15))] = h;
    }

    if (use_th) {
        const _Float16* tb = tempH + ((size_t)n * P + p0) * Q;
#pragma unroll
        for (int t = 0; t < 4; ++t) {
            const int idx = tid + t * 512;          // 2048 half8 groups
            const int row = idx >> 4, hg = idx & 15;
            const half8 hv = ((const half8*)tb)[idx];
            Half4 h1, h2;
            h1.x = hv[0]; h1.y = hv[1]; h1.z = hv[2]; h1.w = hv[3];
            h2.x = hv[4]; h2.y = hv[5]; h2.z = hv[6]; h2.w = hv[7];
            const int rx = row & 15;
            sTh[row * 32 + ((hg * 2) ^ rx)] = h1;
            sTh[row * 32 + ((hg * 2 + 1) ^ rx)] = h2;
        }
    } else {
        const float lr = *lrp;
        const float* xb = X + (size_t)n * P * Q + (size_t)p0 * Q;
        const float* gb = G + (size_t)n * P * Q + (size_t)p0 * Q;
#pragma unroll
        for (int t = 0; t < 8; ++t) {
            const int idx = tid + t * 512;
            const int row = idx >> 5, c4 = idx & 31;
            const float4 xv = ((const float4*)xb)[idx];
            const float4 gv = ((const float4*)gb)[idx];
            Half4 h;
            h.x = (_Float16)(xv.x - lr * gv.x);
            h.y = (_Float16)(xv.y - lr * gv.y);
            h.z = (_Float16)(xv.z - lr * gv.z);
            h.w = (_Float16)(xv.w - lr * gv.w);
            sTh[row * 32 + (c4 ^ (row & 15))] = h;
        }
    }
    __syncthreads();

    const int lane = tid & 63;
    const int wid = tid >> 6;
    const int RB = wid * 16;
    const f32x4 zero4 = {0.0f, 0.0f, 0.0f, 0.0f};

    f32x4 a[8];
#pragma unroll
    for (int fj = 0; fj < 8; ++fj) a[fj] = zero4;
#pragma unroll
    for (int kb = 0; kb < 4; ++kb) {
        const half8 af = frag_ld(sTh, RB, kb * 8, lane);
#pragma unroll
        for (int fj = 0; fj < 8; ++fj) {
            const half8 bf = frag_ld(sZh, fj * 16, kb * 8, lane);
            a[fj] = __builtin_amdgcn_mfma_f32_16x16x32_f16(af, bf, a[fj], 0, 0, 0);
        }
    }

    const int m0 = (lane >> 4) * 4;
    const int nn = lane & 15;
#pragma unroll
    for (int fj = 0; fj < 8; ++fj) {
#pragma unroll
        for (int j = 0; j < 4; ++j) {
            ob[(size_t)(RB + m0 + j) * Q + fj * 16 + nn] = a[fj][j];
        }
    }
}

extern "C" void kernel_launch(void* const* d_in, const int* in_sizes, int n_in,
                              void* d_out, int out_size, void* d_ws, size_t ws_size,
                              hipStream_t stream) {
    const float* X  = (const float*)d_in[0];
    const float* G  = (const float*)d_in[1];
    const float* lr = (const float*)d_in[2];
    float* outp = (float*)d_out;

    const size_t QQ = (size_t)Q * Q;
    const size_t mat = (size_t)NBATCH * QQ;              // 16.8 MB as floats
    const size_t thHalves = (size_t)NBATCH * P * Q;      // 33.5M halves = 67 MB

    const int npart_want = 4;
    const size_t need_np = (1 + npart_want) * mat * sizeof(float);
    const int npart = (ws_size >= need_np) ? npart_want : 1;
    const size_t need_th = need_np + thHalves * sizeof(_Float16);
    const int use_th = (npart == npart_want && ws_size >= need_th) ? 1 : 0;

    float* Zg    = (float*)d_ws;
    float* gpart = Zg + mat;
    _Float16* tempH = use_th ? (_Float16*)(gpart + (size_t)npart * mat) : (_Float16*)0;

    gram_kernel<<<NBATCH * npart, 512, 0, stream>>>(X, G, lr, gpart, npart, tempH);
    ns_kernel<<<NBATCH, 512, 0, stream>>>(gpart, npart, Zg);
    apply_kernel<<<NBATCH * 8, 512, 0, stream>>>(X, G, lr, Zg, tempH, use_th, outp);
}

// Round 14
// 224.579 us; speedup vs baseline: 1.0306x; 1.0003x over previous
//
#include <hip/hip_runtime.h>

#define NBATCH 256
#define P 1024
#define Q 128
#define NS_LOOP 8

typedef _Float16 half8 __attribute__((ext_vector_type(8)));
typedef float f32x4 __attribute__((ext_vector_type(4)));
struct __attribute__((aligned(8))) Half4 { _Float16 x, y, z, w; };   // 8 bytes

// raw workgroup barrier without HIP's implicit vmcnt(0) drain.
__device__ __forceinline__ void barrier_lds_only() {
    asm volatile("s_waitcnt lgkmcnt(0)" ::: "memory");
    __builtin_amdgcn_s_barrier();
    asm volatile("" ::: "memory");
}
__device__ __forceinline__ void barrier_plain() {
    asm volatile("" ::: "memory");
    __builtin_amdgcn_s_barrier();
    asm volatile("" ::: "memory");
}

// ---- swizzled fp16 machinery for ns/apply (counter-clean since r6) ----
__device__ __forceinline__ half8 frag_ld(const Half4* S, int rowbase, int slotbase, int lane) {
    const int r = rowbase + (lane & 15);
    const int g = (lane >> 4);
    const int rx = r & 15;
    const Half4 h1 = S[r * 32 + ((slotbase + g) ^ rx)];
    const Half4 h2 = S[r * 32 + ((slotbase + g + 4) ^ rx)];
    half8 v;
    v[0] = h1.x; v[1] = h1.y; v[2] = h1.z; v[3] = h1.w;
    v[4] = h2.x; v[5] = h2.y; v[6] = h2.z; v[7] = h2.w;
    return v;
}

__device__ __forceinline__ int cpos(int RB, int CB, int lane) {
    const int r = CB + (lane & 15);
    const int s = (RB >> 2) + (lane >> 4);
    return r * 32 + (s ^ (r & 15));
}

__device__ __forceinline__ f32x4 cread(const Half4* S, int p) {
    const Half4 h = S[p];
    f32x4 v;
    v[0] = (float)h.x; v[1] = (float)h.y; v[2] = (float)h.z; v[3] = (float)h.w;
    return v;
}

__device__ __forceinline__ void cwrite(Half4* S, int p, f32x4 v) {
    Half4 h;
    h.x = (_Float16)v[0]; h.y = (_Float16)v[1]; h.z = (_Float16)v[2]; h.w = (_Float16)v[3];
    S[p] = h;
}

__device__ __forceinline__ void cwrite_hl(Half4* Sh, Half4* Sl, int p, f32x4 v) {
    Half4 h, l;
    h.x = (_Float16)v[0]; h.y = (_Float16)v[1]; h.z = (_Float16)v[2]; h.w = (_Float16)v[3];
    l.x = (_Float16)(v[0] - (float)h.x);
    l.y = (_Float16)(v[1] - (float)h.y);
    l.z = (_Float16)(v[2] - (float)h.z);
    l.w = (_Float16)(v[3] - (float)h.w);
    Sh[p] = h; Sl[p] = l;
}

// ---- pitch-36 transposed fragment read for gram, with p-group XOR swizzle.
// Write side stores T[p][q] at sX[q*36 + (p ^ ((q>>2 & 7)<<2))]; reading the
// Half4 group (g ^ xg) returns logical halves [4g..4g+3] (involution).
__device__ __forceinline__ half8 frag_ld36s(const _Float16* S, int rowbase, int lane) {
    const int r = rowbase + (lane & 15);
    const int g = lane >> 4;
    const int xg = (r >> 2) & 7;
    const Half4 h1 = *(const Half4*)(S + r * 36 + 4 * (g ^ xg));
    const Half4 h2 = *(const Half4*)(S + r * 36 + 4 * ((g + 4) ^ xg));
    half8 v;
    v[0] = h1.x; v[1] = h1.y; v[2] = h1.z; v[3] = h1.w;
    v[4] = h2.x; v[5] = h2.y; v[6] = h2.z; v[7] = h2.w;
    return v;
}

// ---- gram helpers: float4-grain memory path (r14) ----
// Thread owns rows pa and pa+16 at float4-column q4 of each 32-row chunk.
__device__ __forceinline__ void gload4(const float* __restrict__ xb,
    const float* __restrict__ gb, float lr, int pbase, int pa, int q4, float4* tv)
{
#pragma unroll
    for (int t = 0; t < 2; ++t) {
        const int p = pa + t * 16;
        const float4 xv = ((const float4*)(xb + (size_t)(pbase + p) * Q))[q4];
        const float4 gv = ((const float4*)(gb + (size_t)(pbase + p) * Q))[q4];
        tv[t] = make_float4(xv.x - lr * gv.x, xv.y - lr * gv.y,
                            xv.z - lr * gv.z, xv.w - lr * gv.w);
    }
}

__device__ __forceinline__ void gstore4(_Float16* sHi, _Float16* sLo,
    int pa, int q4, const float4* tv, _Float16* __restrict__ th, int pbase)
{
    const int x = (q4 & 7) << 2;     // p-group XOR swizzle (matches frag_ld36s)
#pragma unroll
    for (int t = 0; t < 2; ++t) {
        const int p = pa + t * 16;
        const float v[4] = {tv[t].x, tv[t].y, tv[t].z, tv[t].w};
        Half4 hh;
        _Float16* hp = (_Float16*)&hh;
        _Float16 lo[4];
#pragma unroll
        for (int i = 0; i < 4; ++i) {
            hp[i] = (_Float16)v[i];
            lo[i] = (_Float16)(v[i] - (float)hp[i]);
        }
        if (th) *(Half4*)(th + (size_t)(pbase + p) * Q + 4 * q4) = hh;  // 8B store
        const int pp = p ^ x;
#pragma unroll
        for (int i = 0; i < 4; ++i) {
            const int q = 4 * q4 + i;
            sHi[q * 36 + pp] = hp[i];
            sLo[q * 36 + pp] = lo[i];
        }
    }
}

__device__ __forceinline__ void gram_mfma(const _Float16* sHi, const _Float16* sLo,
    int RB, int lane, f32x4* acc)
{
    const half8 ahi = frag_ld36s(sHi, RB, lane);
    const half8 alo = frag_ld36s(sLo, RB, lane);
#pragma unroll
    for (int fj = 0; fj < 8; ++fj) {
        const half8 bhi = frag_ld36s(sHi, fj * 16, lane);
        const half8 blo = frag_ld36s(sLo, fj * 16, lane);
        acc[fj] = __builtin_amdgcn_mfma_f32_16x16x32_f16(ahi, bhi, acc[fj], 0, 0, 0);
        acc[fj] = __builtin_amdgcn_mfma_f32_16x16x32_f16(ahi, blo, acc[fj], 0, 0, 0);
        acc[fj] = __builtin_amdgcn_mfma_f32_16x16x32_f16(alo, bhi, acc[fj], 0, 0, 0);
    }
}

// ---------------------------------------------------------------------------
// Kernel 1: partial gram, fp16 MFMA hi/lo. r14: float4-grain global loads
// (4 instr/thread/chunk, was 16), Half4 tempH stores (2, was 8), b16
// transposed LDS writes with XOR swizzle (~8-way, bounded). r13 was bound on
// fine-grained VMEM issue (213B/instr avg, all pipes <30%).
// ---------------------------------------------------------------------------
__global__ __launch_bounds__(512) void gram_kernel(
    const float* __restrict__ X, const float* __restrict__ G,
    const float* __restrict__ lrp, float* __restrict__ gpart, int npart,
    _Float16* __restrict__ tempH)
{
    __shared__ _Float16 sHi[128 * 36];
    __shared__ _Float16 sLo[128 * 36];

    const int n = blockIdx.x / npart;
    const int part = blockIdx.x - n * npart;
    const int rows = P / npart;
    const float lr = *lrp;
    const float* xb = X + (size_t)n * P * Q;
    const float* gb = G + (size_t)n * P * Q;
    _Float16* th = tempH ? tempH + (size_t)n * P * Q : (_Float16*)0;

    const int tid = threadIdx.x;
    const int lane = tid & 63;
    const int wid = tid >> 6;
    const int RB = wid * 16;
    const int q4 = tid & 31;         // float4 column 0..31
    const int pa = tid >> 5;         // row 0..15 (second row = pa+16)

    const f32x4 zero4 = {0.0f, 0.0f, 0.0f, 0.0f};
    f32x4 acc[8];
#pragma unroll
    for (int fj = 0; fj < 8; ++fj) acc[fj] = zero4;

    const int pstart = part * rows;
    const int nch = rows / 32;       // even

    float4 tA[2], tB[2];
    gload4(xb, gb, lr, pstart, pa, q4, tA);

    for (int c = 0; c < nch; c += 2) {
        barrier_plain();
        gstore4(sHi, sLo, pa, q4, tA, th, pstart + c * 32);
        if (c + 1 < nch) gload4(xb, gb, lr, pstart + (c + 1) * 32, pa, q4, tB);
        barrier_lds_only();
        gram_mfma(sHi, sLo, RB, lane, acc);

        barrier_plain();
        gstore4(sHi, sLo, pa, q4, tB, th, pstart + (c + 1) * 32);
        if (c + 2 < nch) gload4(xb, gb, lr, pstart + (c + 2) * 32, pa, q4, tA);
        barrier_lds_only();
        gram_mfma(sHi, sLo, RB, lane, acc);
    }

    float* gm = gpart + ((size_t)n * npart + part) * Q * Q;
    const int m0 = (lane >> 4) * 4;
    const int nn = lane & 15;
#pragma unroll
    for (int fj = 0; fj < 8; ++fj) {
#pragma unroll
        for (int j = 0; j < 4; ++j) {
            gm[(size_t)(RB + m0 + j) * Q + fj * 16 + nn] = acc[fj][j];
        }
    }
}

// ---------------------------------------------------------------------------
// Kernel 2: Newton-Schulz (fp16 MFMA) + fused fp32-grade refinement (r11-13).
// ---------------------------------------------------------------------------
__global__ __launch_bounds__(512) void ns_kernel(
    const float* __restrict__ gpart, int npart, float* __restrict__ Zg)
{
    __shared__ __align__(16) unsigned char pool[163840];
    Half4* bufA = (Half4*)pool;
    Half4* bufB = (Half4*)(pool + 32768);
    Half4* sZh  = (Half4*)(pool + 65536);
    Half4* bufC = (Half4*)(pool + 98304);
    Half4* bufD = (Half4*)(pool + 131072);
    float* sRed = (float*)pool;

    const int n = blockIdx.x;
    const int tid = threadIdx.x;
    const float* gp = gpart + (size_t)n * npart * Q * Q;

    float4 gv[8];
    float ss = 0.0f;
#pragma unroll
    for (int t = 0; t < 8; ++t) {
        const int idx = tid + t * 512;
        float4 v = ((const float4*)gp)[idx];
        for (int pp = 1; pp < npart; ++pp) {
            const float4 w = ((const float4*)(gp + (size_t)pp * Q * Q))[idx];
            v.x += w.x; v.y += w.y; v.z += w.z; v.w += w.w;
        }
        gv[t] = v;
        ss += v.x * v.x + v.y * v.y + v.z * v.z + v.w * v.w;
    }
#pragma unroll
    for (int off = 32; off > 0; off >>= 1) ss += __shfl_down(ss, off, 64);
    if ((tid & 63) == 0) sRed[tid >> 6] = ss;
    __syncthreads();
    float csum = 0.0f;
#pragma unroll
    for (int w = 0; w < 8; ++w) csum += sRed[w];
    __syncthreads();
    const float c = sqrtf(csum);
    const float rc = 1.0f / c;
    const float rs = 1.0f / sqrtf(c);

#pragma unroll
    for (int t = 0; t < 8; ++t) {
        const int idx = tid + t * 512;
        const int row = idx >> 5, c4 = idx & 31;
        const int slot = row * 32 + (c4 ^ (row & 15));
        float wv[4], zv[4];
        wv[0] = gv[t].x * rc; wv[1] = gv[t].y * rc;
        wv[2] = gv[t].z * rc; wv[3] = gv[t].w * rc;
        Half4 wh, wl, zh;
        _Float16* whp = (_Float16*)&wh;
        _Float16* wlp = (_Float16*)&wl;
        _Float16* zhp = (_Float16*)&zh;
#pragma unroll
        for (int j = 0; j < 4; ++j) {
            const _Float16 h = (_Float16)wv[j];
            whp[j] = h;
            wlp[j] = (_Float16)(wv[j] - (float)h);
            zv[j] = -0.5f * wv[j] + (((row >> 2) == c4 && (row & 3) == j) ? 1.5f : 0.0f);
            zhp[j] = (_Float16)zv[j];
        }
        bufA[slot] = wh;
        bufC[slot] = wh;
        bufD[slot] = wl;
        sZh[slot] = zh;
    }
    __syncthreads();

    const int lane = tid & 63;
    const int wid = tid >> 6;
    const int RB = wid * 16;
    const f32x4 zero4 = {0.0f, 0.0f, 0.0f, 0.0f};
    Half4* cur = bufA;
    Half4* scr = bufB;

    for (int it = 0; it < NS_LOOP; ++it) {
        f32x4 a1[8];
#pragma unroll
        for (int fj = 0; fj < 8; ++fj) a1[fj] = zero4;
#pragma unroll
        for (int kb = 0; kb < 4; ++kb) {
            const half8 af = frag_ld(cur, RB, kb * 8, lane);
#pragma unroll
            for (int fj = 0; fj < 8; ++fj) {
                const half8 bf = frag_ld(cur, fj * 16, kb * 8, lane);
                a1[fj] = __builtin_amdgcn_mfma_f32_16x16x32_f16(af, bf, a1[fj], 0, 0, 0);
            }
        }
#pragma unroll
        for (int fj = 0; fj < 8; ++fj) {
            const int p = cpos(RB, fj * 16, lane);
            cwrite(scr, p, 1.5f * cread(cur, p) - 0.5f * a1[fj]);
        }
        __syncthreads();

        f32x4 a2[8];
#pragma unroll
        for (int fj = 0; fj < 8; ++fj) a2[fj] = zero4;
#pragma unroll
        for (int kb = 0; kb < 4; ++kb) {
            const half8 af = frag_ld(scr, RB, kb * 8, lane);
#pragma unroll
            for (int fj = 0; fj < 8; ++fj) {
                const half8 bf = frag_ld(cur, fj * 16, kb * 8, lane);
                a2[fj] = __builtin_amdgcn_mfma_f32_16x16x32_f16(af, bf, a2[fj], 0, 0, 0);
            }
        }
        f32x4 wn[8];
#pragma unroll
        for (int fj = 0; fj < 8; ++fj) {
            const int p = cpos(RB, fj * 16, lane);
            wn[fj] = 1.5f * cread(scr, p) - 0.5f * a2[fj];
        }
        __syncthreads();
#pragma unroll
        for (int fj = 0; fj < 8; ++fj)
            cwrite(scr, cpos(RB, fj * 16, lane), wn[fj]);
        __syncthreads();

        f32x4 a3[8];
#pragma unroll
        for (int fj = 0; fj < 8; ++fj) a3[fj] = zero4;
#pragma unroll
        for (int kb = 0; kb < 4; ++kb) {
            const half8 af = frag_ld(scr, RB, kb * 8, lane);
#pragma unroll
            for (int fj = 0; fj < 8; ++fj) {
                const half8 bf = frag_ld(sZh, fj * 16, kb * 8, lane);
                a3[fj] = __builtin_amdgcn_mfma_f32_16x16x32_f16(af, bf, a3[fj], 0, 0, 0);
            }
        }
        f32x4 zn[8];
#pragma unroll
        for (int fj = 0; fj < 8; ++fj) {
            const int p = cpos(RB, fj * 16, lane);
            zn[fj] = 1.5f * cread(sZh, p) - 0.5f * a3[fj];
        }
        __syncthreads();
#pragma unroll
        for (int fj = 0; fj < 8; ++fj)
            cwrite(sZh, cpos(RB, fj * 16, lane), zn[fj]);
        __syncthreads();

        Half4* tmp = cur; cur = scr; scr = tmp;
    }

    // symmetrize z exactly
    {
        _Float16* zp = (_Float16*)sZh;
        for (int k = tid; k < Q * Q; k += 512) {
            const int r = k >> 7, cc = k & 127;
            if (r < cc) {
                const int i1 = (r * 32 + ((cc >> 2) ^ (r & 15))) * 4 + (cc & 3);
                const int i2 = (cc * 32 + ((r >> 2) ^ (cc & 15))) * 4 + (r & 3);
                const _Float16 av = (_Float16)(0.5f * ((float)zp[i1] + (float)zp[i2]));
                zp[i1] = av; zp[i2] = av;
            }
        }
    }
    __syncthreads();

    // racc = A*z -> cpos store = rows of (z*A)
    f32x4 racc[8];
#pragma unroll
    for (int fj = 0; fj < 8; ++fj) racc[fj] = zero4;
#pragma unroll
    for (int kb = 0; kb < 4; ++kb) {
        const half8 ah = frag_ld(bufC, RB, kb * 8, lane);
        const half8 al = frag_ld(bufD, RB, kb * 8, lane);
#pragma unroll
        for (int fj = 0; fj < 8; ++fj) {
            const half8 bz = frag_ld(sZh, fj * 16, kb * 8, lane);
            racc[fj] = __builtin_amdgcn_mfma_f32_16x16x32_f16(ah, bz, racc[fj], 0, 0, 0);
            racc[fj] = __builtin_amdgcn_mfma_f32_16x16x32_f16(al, bz, racc[fj], 0, 0, 0);
        }
    }
#pragma unroll
    for (int fj = 0; fj < 8; ++fj)
        cwrite_hl(bufA, bufB, cpos(RB, fj * 16, lane), racc[fj]);
    __syncthreads();

    // uacc = z*z -> bufC/bufD hi/lo
    f32x4 uacc[8];
#pragma unroll
    for (int fj = 0; fj < 8; ++fj) uacc[fj] = zero4;
#pragma unroll
    for (int kb = 0; kb < 4; ++kb) {
        const half8 az = frag_ld(sZh, RB, kb * 8, lane);
#pragma unroll
        for (int fj = 0; fj < 8; ++fj) {
            const half8 bz = frag_ld(sZh, fj * 16, kb * 8, lane);
            uacc[fj] = __builtin_amdgcn_mfma_f32_16x16x32_f16(az, bz, uacc[fj], 0, 0, 0);
        }
    }
#pragma unroll
    for (int fj = 0; fj < 8; ++fj)
        cwrite_hl(bufC, bufD, cpos(RB, fj * 16, lane), uacc[fj]);
    __syncthreads();

    // d = (z*A)*u ; Z_ref = rs*(1.5 z - 0.5 d)
    f32x4 dacc[8];
#pragma unroll
    for (int fj = 0; fj < 8; ++fj) dacc[fj] = zero4;
#pragma unroll
    for (int kb = 0; kb < 4; ++kb) {
        const half8 rh = frag_ld(bufA, RB, kb * 8, lane);
        const half8 rl = frag_ld(bufB, RB, kb * 8, lane);
#pragma unroll
        for (int fj = 0; fj < 8; ++fj) {
            const half8 uh = frag_ld(bufC, fj * 16, kb * 8, lane);
            const half8 ul = frag_ld(bufD, fj * 16, kb * 8, lane);
            dacc[fj] = __builtin_amdgcn_mfma_f32_16x16x32_f16(rh, uh, dacc[fj], 0, 0, 0);
            dacc[fj] = __builtin_amdgcn_mfma_f32_16x16x32_f16(rh, ul, dacc[fj], 0, 0, 0);
            dacc[fj] = __builtin_amdgcn_mfma_f32_16x16x32_f16(rl, uh, dacc[fj], 0, 0, 0);
        }
    }

    float* zo = Zg + (size_t)n * Q * Q;
    const int m0 = (lane >> 4) * 4;
    const int nn = lane & 15;
#pragma unroll
    for (int fj = 0; fj < 8; ++fj) {
        const f32x4 zq = cread(sZh, cpos(RB, fj * 16, lane));
#pragma unroll
        for (int j = 0; j < 4; ++j) {
            zo[(size_t)(RB + m0 + j) * Q + fj * 16 + nn] =
                rs * (1.5f * zq[j] - 0.5f * dacc[fj][j]);
        }
    }
}

// ---------------------------------------------------------------------------
// Kernel 3: out[n] = temp[n] @ Zg[n], fp16 MFMA; tempH fast path (r13).
// ---------------------------------------------------------------------------
__global__ __launch_bounds__(512) void apply_kernel(
    const float* __restrict__ X, const float* __restrict__ G,
    const float* __restrict__ lrp, const float* __restrict__ Zg,
    const _Float16* __restrict__ tempH, int use_th,
    float* __restrict__ out)
{
    __shared__ __align__(16) unsigned char pool[65536];
    Half4* sTh = (Half4*)pool;
    Half4* sZh = (Half4*)(pool + 32768);

    const int n = blockIdx.x >> 3;
    const int p0 = (blockIdx.x & 7) * 128;
    const int tid = threadIdx.x;
    const float* zb = Zg + (size_t)n * Q * Q;
    float* ob = out + (size_t)n * P * Q + (size_t)p0 * Q;

#pragma unroll
    for (int t = 0; t < 8; ++t) {
        const int idx = tid + t * 512;
        const int row = idx >> 5, c4 = idx & 31;
        const float4 v = ((const float4*)zb)[idx];
        Half4 h;
        h.x = (_Float16)v.x; h.y = (_Float16)v.y;
        h.z = (_Float16)v.z; h.w = (_Float16)v.w;
        sZh[row * 32 + (c4 ^ (row & 15))] = h;
    }

    if (use_th) {
        const _Float16* tb = tempH + ((size_t)n * P + p0) * Q;
#pragma unroll
        for (int t = 0; t < 4; ++t) {
            const int idx = tid + t * 512;
            const int row = idx >> 4, hg = idx & 15;
            const half8 hv = ((const half8*)tb)[idx];
            Half4 h1, h2;
            h1.x = hv[0]; h1.y = hv[1]; h1.z = hv[2]; h1.w = hv[3];
            h2.x = hv[4]; h2.y = hv[5]; h2.z = hv[6]; h2.w = hv[7];
            const int rx = row & 15;
            sTh[row * 32 + ((hg * 2) ^ rx)] = h1;
            sTh[row * 32 + ((hg * 2 + 1) ^ rx)] = h2;
        }
    } else {
        const float lr = *lrp;
        const float* xb = X + (size_t)n * P * Q + (size_t)p0 * Q;
        const float* gb = G + (size_t)n * P * Q + (size_t)p0 * Q;
#pragma unroll
        for (int t = 0; t < 8; ++t) {
            const int idx = tid + t * 512;
            const int row = idx >> 5, c4 = idx & 31;
            const float4 xv = ((const float4*)xb)[idx];
            const float4 gv = ((const float4*)gb)[idx];
            Half4 h;
            h.x = (_Float16)(xv.x - lr * gv.x);
            h.y = (_Float16)(xv.y - lr * gv.y);
            h.z = (_Float16)(xv.z - lr * gv.z);
            h.w = (_Float16)(xv.w - lr * gv.w);
            sTh[row * 32 + (c4 ^ (row & 15))] = h;
        }
    }
    __syncthreads();

    const int lane = tid & 63;
    const int wid = tid >> 6;
    const int RB = wid * 16;
    const f32x4 zero4 = {0.0f, 0.0f, 0.0f, 0.0f};

    f32x4 a[8];
#pragma unroll
    for (int fj = 0; fj < 8; ++fj) a[fj] = zero4;
#pragma unroll
    for (int kb = 0; kb < 4; ++kb) {
        const half8 af = frag_ld(sTh, RB, kb * 8, lane);
#pragma unroll
        for (int fj = 0; fj < 8; ++fj) {
            const half8 bf = frag_ld(sZh, fj * 16, kb * 8, lane);
            a[fj] = __builtin_amdgcn_mfma_f32_16x16x32_f16(af, bf, a[fj], 0, 0, 0);
        }
    }

    const int m0 = (lane >> 4) * 4;
    const int nn = lane & 15;
#pragma unroll
    for (int fj = 0; fj < 8; ++fj) {
#pragma unroll
        for (int j = 0; j < 4; ++j) {
            ob[(size_t)(RB + m0 + j) * Q + fj * 16 + nn] = a[fj][j];
        }
    }
}

extern "C" void kernel_launch(void* const* d_in, const int* in_sizes, int n_in,
                              void* d_out, int out_size, void* d_ws, size_t ws_size,
                              hipStream_t stream) {
    const float* X  = (const float*)d_in[0];
    const float* G  = (const float*)d_in[1];
    const float* lr = (const float*)d_in[2];
    float* outp = (float*)d_out;

    const size_t QQ = (size_t)Q * Q;
    const size_t mat = (size_t)NBATCH * QQ;
    const size_t thHalves = (size_t)NBATCH * P * Q;

    const int npart_want = 4;
    const size_t need_np = (1 + npart_want) * mat * sizeof(float);
    const int npart = (ws_size >= need_np) ? npart_want : 1;
    const size_t need_th = need_np + thHalves * sizeof(_Float16);
    const int use_th = (npart == npart_want && ws_size >= need_th) ? 1 : 0;

    float* Zg    = (float*)d_ws;
    float* gpart = Zg + mat;
    _Float16* tempH = use_th ? (_Float16*)(gpart + (size_t)npart * mat) : (_Float16*)0;

    gram_kernel<<<NBATCH * npart, 512, 0, stream>>>(X, G, lr, gpart, npart, tempH);
    ns_kernel<<<NBATCH, 512, 0, stream>>>(gpart, npart, Zg);
    apply_kernel<<<NBATCH * 8, 512, 0, stream>>>(X, G, lr, Zg, tempH, use_th, outp);
}